// Round 1
// baseline (1079.432 us; speedup 1.0000x reference)
//
#include <hip/hip_runtime.h>

// GridPull: trilinear interpolation, dct2 reflect boundary, extrapolate=True.
// x: (1, 2, 192, 192, 192) f32; grid: (1, 192, 192, 192, 3) f32 voxel coords.
// out: (1, 2, 192, 192, 192) f32.

constexpr int DIM = 192;
constexpr int N = DIM * DIM * DIM;       // voxels
constexpr int C = 2;

__device__ __forceinline__ int reflect_dct2(int i, int n) {
    // symmetric about -0.5 and n-0.5, period 2n; matches jnp.mod then fold
    const int p = 2 * n;
    i = ((i % p) + p) % p;               // nonnegative
    return (i >= n) ? (p - 1 - i) : i;
}

__global__ __launch_bounds__(256) void grid_pull_kernel(
        const float* __restrict__ x,     // (C, N)
        const float* __restrict__ grid,  // (N, 3)
        float* __restrict__ out) {       // (C, N)
    const int n = blockIdx.x * blockDim.x + threadIdx.x;
    if (n >= N) return;

    const float gx = grid[3 * n + 0];
    const float gy = grid[3 * n + 1];
    const float gz = grid[3 * n + 2];

    const float fx = floorf(gx), fy = floorf(gy), fz = floorf(gz);
    const int lx = (int)fx, ly = (int)fy, lz = (int)fz;
    const float tx = gx - fx, ty = gy - fy, tz = gz - fz;

    const int ix0 = reflect_dct2(lx,     DIM);
    const int ix1 = reflect_dct2(lx + 1, DIM);
    const int iy0 = reflect_dct2(ly,     DIM);
    const int iy1 = reflect_dct2(ly + 1, DIM);
    const int iz0 = reflect_dct2(lz,     DIM);
    const int iz1 = reflect_dct2(lz + 1, DIM);

    const float wx0 = 1.0f - tx, wx1 = tx;
    const float wy0 = 1.0f - ty, wy1 = ty;
    const float wz0 = 1.0f - tz, wz1 = tz;

    // row bases (x-plane and y-row offsets)
    const int bx0 = ix0 * (DIM * DIM), bx1 = ix1 * (DIM * DIM);
    const int by0 = iy0 * DIM,         by1 = iy1 * DIM;

    const int i000 = bx0 + by0 + iz0;
    const int i001 = bx0 + by0 + iz1;
    const int i010 = bx0 + by1 + iz0;
    const int i011 = bx0 + by1 + iz1;
    const int i100 = bx1 + by0 + iz0;
    const int i101 = bx1 + by0 + iz1;
    const int i110 = bx1 + by1 + iz0;
    const int i111 = bx1 + by1 + iz1;

    const float w000 = wx0 * wy0 * wz0;
    const float w001 = wx0 * wy0 * wz1;
    const float w010 = wx0 * wy1 * wz0;
    const float w011 = wx0 * wy1 * wz1;
    const float w100 = wx1 * wy0 * wz0;
    const float w101 = wx1 * wy0 * wz1;
    const float w110 = wx1 * wy1 * wz0;
    const float w111 = wx1 * wy1 * wz1;

#pragma unroll
    for (int c = 0; c < C; ++c) {
        const float* __restrict__ xc = x + (size_t)c * N;
        float acc = xc[i000] * w000;
        acc += xc[i001] * w001;
        acc += xc[i010] * w010;
        acc += xc[i011] * w011;
        acc += xc[i100] * w100;
        acc += xc[i101] * w101;
        acc += xc[i110] * w110;
        acc += xc[i111] * w111;
        out[(size_t)c * N + n] = acc;
    }
}

extern "C" void kernel_launch(void* const* d_in, const int* in_sizes, int n_in,
                              void* d_out, int out_size, void* d_ws, size_t ws_size,
                              hipStream_t stream) {
    const float* x    = (const float*)d_in[0];
    const float* grid = (const float*)d_in[1];
    float* out        = (float*)d_out;

    const int threads = 256;
    const int blocks = (N + threads - 1) / threads;
    grid_pull_kernel<<<blocks, threads, 0, stream>>>(x, grid, out);
}

// Round 2
// 648.995 us; speedup vs baseline: 1.6632x; 1.6632x over previous
//
#include <hip/hip_runtime.h>

// GridPull: trilinear interpolation, dct2 reflect boundary, extrapolate=True.
// x: (1, 2, 192, 192, 192) f32; grid: (1, 192, 192, 192, 3) f32 voxel coords.
// out: (1, 2, 192, 192, 192) f32.
//
// R2: repack x planar (C,N) -> interleaved (N,C) float2 in d_ws, so each
// gathered corner serves both channels with one 8B load -> 4 cachelines/voxel
// instead of 8. Gather traffic ~3.5 GB -> ~1.8 GB.

constexpr int DIM = 192;
constexpr int N = DIM * DIM * DIM;       // voxels
constexpr int C = 2;

__device__ __forceinline__ int reflect_dct2(int i, int n) {
    const int p = 2 * n;
    i = ((i % p) + p) % p;               // nonnegative
    return (i >= n) ? (p - 1 - i) : i;
}

__global__ __launch_bounds__(256) void repack_kernel(
        const float* __restrict__ x,     // (C, N)
        float2* __restrict__ xi) {       // (N, 2)
    const int n = blockIdx.x * blockDim.x + threadIdx.x;
    if (n >= N) return;
    float2 v;
    v.x = x[n];
    v.y = x[N + n];
    xi[n] = v;
}

__global__ __launch_bounds__(256) void grid_pull_interleaved_kernel(
        const float2* __restrict__ xi,   // (N, 2) channel-interleaved
        const float* __restrict__ grid,  // (N, 3)
        float* __restrict__ out) {       // (C, N)
    const int n = blockIdx.x * blockDim.x + threadIdx.x;
    if (n >= N) return;

    const float gx = grid[3 * n + 0];
    const float gy = grid[3 * n + 1];
    const float gz = grid[3 * n + 2];

    const float fx = floorf(gx), fy = floorf(gy), fz = floorf(gz);
    const int lx = (int)fx, ly = (int)fy, lz = (int)fz;
    const float tx = gx - fx, ty = gy - fy, tz = gz - fz;

    const int ix0 = reflect_dct2(lx,     DIM);
    const int ix1 = reflect_dct2(lx + 1, DIM);
    const int iy0 = reflect_dct2(ly,     DIM);
    const int iy1 = reflect_dct2(ly + 1, DIM);
    const int iz0 = reflect_dct2(lz,     DIM);
    const int iz1 = reflect_dct2(lz + 1, DIM);

    const float wx0 = 1.0f - tx, wx1 = tx;
    const float wy0 = 1.0f - ty, wy1 = ty;
    const float wz0 = 1.0f - tz, wz1 = tz;

    const int bx0 = ix0 * (DIM * DIM), bx1 = ix1 * (DIM * DIM);
    const int by0 = iy0 * DIM,         by1 = iy1 * DIM;

    const float2 v000 = xi[bx0 + by0 + iz0];
    const float2 v001 = xi[bx0 + by0 + iz1];
    const float2 v010 = xi[bx0 + by1 + iz0];
    const float2 v011 = xi[bx0 + by1 + iz1];
    const float2 v100 = xi[bx1 + by0 + iz0];
    const float2 v101 = xi[bx1 + by0 + iz1];
    const float2 v110 = xi[bx1 + by1 + iz0];
    const float2 v111 = xi[bx1 + by1 + iz1];

    const float w000 = wx0 * wy0 * wz0;
    const float w001 = wx0 * wy0 * wz1;
    const float w010 = wx0 * wy1 * wz0;
    const float w011 = wx0 * wy1 * wz1;
    const float w100 = wx1 * wy0 * wz0;
    const float w101 = wx1 * wy0 * wz1;
    const float w110 = wx1 * wy1 * wz0;
    const float w111 = wx1 * wy1 * wz1;

    float acc0 = v000.x * w000 + v001.x * w001 + v010.x * w010 + v011.x * w011
               + v100.x * w100 + v101.x * w101 + v110.x * w110 + v111.x * w111;
    float acc1 = v000.y * w000 + v001.y * w001 + v010.y * w010 + v011.y * w011
               + v100.y * w100 + v101.y * w101 + v110.y * w110 + v111.y * w111;

    out[n]     = acc0;
    out[N + n] = acc1;
}

// Fallback (R1 kernel) if workspace is too small for the interleaved copy.
__global__ __launch_bounds__(256) void grid_pull_planar_kernel(
        const float* __restrict__ x,
        const float* __restrict__ grid,
        float* __restrict__ out) {
    const int n = blockIdx.x * blockDim.x + threadIdx.x;
    if (n >= N) return;

    const float gx = grid[3 * n + 0];
    const float gy = grid[3 * n + 1];
    const float gz = grid[3 * n + 2];

    const float fx = floorf(gx), fy = floorf(gy), fz = floorf(gz);
    const int lx = (int)fx, ly = (int)fy, lz = (int)fz;
    const float tx = gx - fx, ty = gy - fy, tz = gz - fz;

    const int ix0 = reflect_dct2(lx,     DIM);
    const int ix1 = reflect_dct2(lx + 1, DIM);
    const int iy0 = reflect_dct2(ly,     DIM);
    const int iy1 = reflect_dct2(ly + 1, DIM);
    const int iz0 = reflect_dct2(lz,     DIM);
    const int iz1 = reflect_dct2(lz + 1, DIM);

    const float wx0 = 1.0f - tx, wx1 = tx;
    const float wy0 = 1.0f - ty, wy1 = ty;
    const float wz0 = 1.0f - tz, wz1 = tz;

    const int bx0 = ix0 * (DIM * DIM), bx1 = ix1 * (DIM * DIM);
    const int by0 = iy0 * DIM,         by1 = iy1 * DIM;

    const float w000 = wx0 * wy0 * wz0, w001 = wx0 * wy0 * wz1;
    const float w010 = wx0 * wy1 * wz0, w011 = wx0 * wy1 * wz1;
    const float w100 = wx1 * wy0 * wz0, w101 = wx1 * wy0 * wz1;
    const float w110 = wx1 * wy1 * wz0, w111 = wx1 * wy1 * wz1;

#pragma unroll
    for (int c = 0; c < C; ++c) {
        const float* __restrict__ xc = x + (size_t)c * N;
        float acc = xc[bx0 + by0 + iz0] * w000;
        acc += xc[bx0 + by0 + iz1] * w001;
        acc += xc[bx0 + by1 + iz0] * w010;
        acc += xc[bx0 + by1 + iz1] * w011;
        acc += xc[bx1 + by0 + iz0] * w100;
        acc += xc[bx1 + by0 + iz1] * w101;
        acc += xc[bx1 + by1 + iz0] * w110;
        acc += xc[bx1 + by1 + iz1] * w111;
        out[(size_t)c * N + n] = acc;
    }
}

extern "C" void kernel_launch(void* const* d_in, const int* in_sizes, int n_in,
                              void* d_out, int out_size, void* d_ws, size_t ws_size,
                              hipStream_t stream) {
    const float* x    = (const float*)d_in[0];
    const float* grid = (const float*)d_in[1];
    float* out        = (float*)d_out;

    const int threads = 256;
    const int blocks = (N + threads - 1) / threads;
    const size_t need = (size_t)N * C * sizeof(float);

    if (ws_size >= need) {
        float2* xi = (float2*)d_ws;
        repack_kernel<<<blocks, threads, 0, stream>>>(x, xi);
        grid_pull_interleaved_kernel<<<blocks, threads, 0, stream>>>(xi, grid, out);
    } else {
        grid_pull_planar_kernel<<<blocks, threads, 0, stream>>>(x, grid, out);
    }
}

// Round 3
// 412.237 us; speedup vs baseline: 2.6185x; 1.5743x over previous
//
#include <hip/hip_runtime.h>
#include <hip/hip_fp16.h>

// GridPull: trilinear interpolation, dct2 reflect boundary, extrapolate=True.
// x: (1, 2, 192, 192, 192) f32; grid: (1, 192, 192, 192, 3) f32 voxel coords.
// out: (1, 2, 192, 192, 192) f32.
//
// R3: repack x into fp16 channel-pairs arranged in 4x2x2-voxel bricks so one
// 64B cacheline holds a 4(x) x 2(y) x 2(z) neighborhood of both channels.
// Expected distinct lines per sample: (1+1/4)(1+1/2)(1+1/2) = 2.81 vs 4.0
// for the flat (N,2) f32 layout, and the array shrinks 113 MB -> 28.3 MB
// (vs 32 MB aggregate L2). Nontemporal hints keep grid/out streams from
// evicting the brick array out of L2.

constexpr int DIM = 192;
constexpr int N = DIM * DIM * DIM;       // voxels
constexpr int C = 2;

// brick geometry: 4 voxels along x, 2 along y, 2 along z; 16 voxels * half2 = 64B
constexpr int NBX = DIM / 4;             // 48
constexpr int NBY = DIM / 2;             // 96
constexpr int NBZ = DIM / 2;             // 96
constexpr int NBRICKS = NBX * NBY * NBZ; // 442368
// strides in half2 (=uint32) units
constexpr int XSTRIDE = NBY * NBZ * 16;  // per +4 in ix: 147456
constexpr int YSTRIDE = NBZ * 16;        // per +2 in iy: 1536
constexpr int ZSTRIDE = 16;              // per +2 in iz

__device__ __forceinline__ int reflect_dct2(int i, int n) {
    const int p = 2 * n;
    i = ((i % p) + p) % p;               // nonnegative
    return (i >= n) ? (p - 1 - i) : i;
}

// separable brick-address terms
__device__ __forceinline__ int xterm(int ix) { return (ix >> 2) * XSTRIDE + ((ix & 3) << 2); }
__device__ __forceinline__ int yterm(int iy) { return (iy >> 1) * YSTRIDE + ((iy & 1) << 1); }
__device__ __forceinline__ int zterm(int iz) { return (iz >> 1) * ZSTRIDE + (iz & 1); }

__global__ __launch_bounds__(256) void repack_brick_kernel(
        const float* __restrict__ x,     // (C, N) planar
        uint32_t* __restrict__ xb) {     // bricked half2
    const int b = blockIdx.x * blockDim.x + threadIdx.x;
    if (b >= NBRICKS) return;
    const int bz = b % NBZ;
    const int t  = b / NBZ;
    const int by = t % NBY;
    const int bx = t / NBY;
    const int ix0 = bx * 4, iy0 = by * 2, iz0 = bz * 2;

    uint32_t vals[16];
#pragma unroll
    for (int s = 0; s < 16; ++s) {
        const int ix = ix0 + (s >> 2);
        const int iy = iy0 + ((s >> 1) & 1);
        const int iz = iz0 + (s & 1);
        const int n = (ix * DIM + iy) * DIM + iz;
        const __half2 h = __floats2half2_rn(x[n], x[N + n]);
        vals[s] = __builtin_bit_cast(uint32_t, h);
    }
    uint4* dst = (uint4*)(xb + (size_t)b * 16);
    dst[0] = make_uint4(vals[0], vals[1], vals[2], vals[3]);
    dst[1] = make_uint4(vals[4], vals[5], vals[6], vals[7]);
    dst[2] = make_uint4(vals[8], vals[9], vals[10], vals[11]);
    dst[3] = make_uint4(vals[12], vals[13], vals[14], vals[15]);
}

__global__ __launch_bounds__(256) void grid_pull_brick_kernel(
        const uint32_t* __restrict__ xb, // bricked half2
        const float* __restrict__ grid,  // (N, 3)
        float* __restrict__ out) {       // (C, N)
    const int n = blockIdx.x * blockDim.x + threadIdx.x;
    if (n >= N) return;

    const float gx = __builtin_nontemporal_load(&grid[3 * n + 0]);
    const float gy = __builtin_nontemporal_load(&grid[3 * n + 1]);
    const float gz = __builtin_nontemporal_load(&grid[3 * n + 2]);

    const float fx = floorf(gx), fy = floorf(gy), fz = floorf(gz);
    const int lx = (int)fx, ly = (int)fy, lz = (int)fz;
    const float tx = gx - fx, ty = gy - fy, tz = gz - fz;

    const int ix0 = reflect_dct2(lx,     DIM);
    const int ix1 = reflect_dct2(lx + 1, DIM);
    const int iy0 = reflect_dct2(ly,     DIM);
    const int iy1 = reflect_dct2(ly + 1, DIM);
    const int iz0 = reflect_dct2(lz,     DIM);
    const int iz1 = reflect_dct2(lz + 1, DIM);

    const int tx0 = xterm(ix0), tx1 = xterm(ix1);
    const int ty0 = yterm(iy0), ty1 = yterm(iy1);
    const int tz0 = zterm(iz0), tz1 = zterm(iz1);

    const uint32_t u000 = xb[tx0 + ty0 + tz0];
    const uint32_t u001 = xb[tx0 + ty0 + tz1];
    const uint32_t u010 = xb[tx0 + ty1 + tz0];
    const uint32_t u011 = xb[tx0 + ty1 + tz1];
    const uint32_t u100 = xb[tx1 + ty0 + tz0];
    const uint32_t u101 = xb[tx1 + ty0 + tz1];
    const uint32_t u110 = xb[tx1 + ty1 + tz0];
    const uint32_t u111 = xb[tx1 + ty1 + tz1];

    const float wx0 = 1.0f - tx, wx1 = tx;
    const float wy0 = 1.0f - ty, wy1 = ty;
    const float wz0 = 1.0f - tz, wz1 = tz;

    const float w000 = wx0 * wy0 * wz0;
    const float w001 = wx0 * wy0 * wz1;
    const float w010 = wx0 * wy1 * wz0;
    const float w011 = wx0 * wy1 * wz1;
    const float w100 = wx1 * wy0 * wz0;
    const float w101 = wx1 * wy0 * wz1;
    const float w110 = wx1 * wy1 * wz0;
    const float w111 = wx1 * wy1 * wz1;

    const float2 f000 = __half22float2(__builtin_bit_cast(__half2, u000));
    const float2 f001 = __half22float2(__builtin_bit_cast(__half2, u001));
    const float2 f010 = __half22float2(__builtin_bit_cast(__half2, u010));
    const float2 f011 = __half22float2(__builtin_bit_cast(__half2, u011));
    const float2 f100 = __half22float2(__builtin_bit_cast(__half2, u100));
    const float2 f101 = __half22float2(__builtin_bit_cast(__half2, u101));
    const float2 f110 = __half22float2(__builtin_bit_cast(__half2, u110));
    const float2 f111 = __half22float2(__builtin_bit_cast(__half2, u111));

    const float acc0 = f000.x * w000 + f001.x * w001 + f010.x * w010 + f011.x * w011
                     + f100.x * w100 + f101.x * w101 + f110.x * w110 + f111.x * w111;
    const float acc1 = f000.y * w000 + f001.y * w001 + f010.y * w010 + f011.y * w011
                     + f100.y * w100 + f101.y * w101 + f110.y * w110 + f111.y * w111;

    __builtin_nontemporal_store(acc0, &out[n]);
    __builtin_nontemporal_store(acc1, &out[N + n]);
}

// Fallback (R1 kernel) if workspace is too small for the brick array.
__global__ __launch_bounds__(256) void grid_pull_planar_kernel(
        const float* __restrict__ x,
        const float* __restrict__ grid,
        float* __restrict__ out) {
    const int n = blockIdx.x * blockDim.x + threadIdx.x;
    if (n >= N) return;

    const float gx = grid[3 * n + 0];
    const float gy = grid[3 * n + 1];
    const float gz = grid[3 * n + 2];

    const float fx = floorf(gx), fy = floorf(gy), fz = floorf(gz);
    const int lx = (int)fx, ly = (int)fy, lz = (int)fz;
    const float tx = gx - fx, ty = gy - fy, tz = gz - fz;

    const int ix0 = reflect_dct2(lx,     DIM);
    const int ix1 = reflect_dct2(lx + 1, DIM);
    const int iy0 = reflect_dct2(ly,     DIM);
    const int iy1 = reflect_dct2(ly + 1, DIM);
    const int iz0 = reflect_dct2(lz,     DIM);
    const int iz1 = reflect_dct2(lz + 1, DIM);

    const float wx0 = 1.0f - tx, wx1 = tx;
    const float wy0 = 1.0f - ty, wy1 = ty;
    const float wz0 = 1.0f - tz, wz1 = tz;

    const int bx0 = ix0 * (DIM * DIM), bx1 = ix1 * (DIM * DIM);
    const int by0 = iy0 * DIM,         by1 = iy1 * DIM;

    const float w000 = wx0 * wy0 * wz0, w001 = wx0 * wy0 * wz1;
    const float w010 = wx0 * wy1 * wz0, w011 = wx0 * wy1 * wz1;
    const float w100 = wx1 * wy0 * wz0, w101 = wx1 * wy0 * wz1;
    const float w110 = wx1 * wy1 * wz0, w111 = wx1 * wy1 * wz1;

#pragma unroll
    for (int c = 0; c < C; ++c) {
        const float* __restrict__ xc = x + (size_t)c * N;
        float acc = xc[bx0 + by0 + iz0] * w000;
        acc += xc[bx0 + by0 + iz1] * w001;
        acc += xc[bx0 + by1 + iz0] * w010;
        acc += xc[bx0 + by1 + iz1] * w011;
        acc += xc[bx1 + by0 + iz0] * w100;
        acc += xc[bx1 + by0 + iz1] * w101;
        acc += xc[bx1 + by1 + iz0] * w110;
        acc += xc[bx1 + by1 + iz1] * w111;
        out[(size_t)c * N + n] = acc;
    }
}

extern "C" void kernel_launch(void* const* d_in, const int* in_sizes, int n_in,
                              void* d_out, int out_size, void* d_ws, size_t ws_size,
                              hipStream_t stream) {
    const float* x    = (const float*)d_in[0];
    const float* grid = (const float*)d_in[1];
    float* out        = (float*)d_out;

    const int threads = 256;
    const size_t need = (size_t)NBRICKS * 64;   // 28.3 MB

    if (ws_size >= need) {
        uint32_t* xb = (uint32_t*)d_ws;
        const int rblocks = (NBRICKS + threads - 1) / threads;
        repack_brick_kernel<<<rblocks, threads, 0, stream>>>(x, xb);
        const int gblocks = (N + threads - 1) / threads;
        grid_pull_brick_kernel<<<gblocks, threads, 0, stream>>>(xb, grid, out);
    } else {
        const int gblocks = (N + threads - 1) / threads;
        grid_pull_planar_kernel<<<gblocks, threads, 0, stream>>>(x, grid, out);
    }
}